// Round 5
// baseline (740.560 us; speedup 1.0000x reference)
//
#include <hip/hip_runtime.h>
#include <stdint.h>

typedef unsigned int u32;
typedef unsigned long long u64;
typedef unsigned short u16;

// key = ((b*512 + z/2)*512 + y/2)*512 + x/2  in [0, 2^29)
#define LBITS  14
#define LMASK  ((1u << LBITS) - 1u)
#define NBUCK  (1u << (29 - LBITS))      // 32768 buckets
#define BWORDS (1u << (LBITS - 5))       // 512 u32 bitmap words / bucket
#define WPL    (BWORDS / 64)             // 8 words per lane
#define FCAP   320                       // LDS feats slots per bucket
#define BPB    4                         // buckets (waves) per 256-thr block

__device__ __forceinline__ u32 make_key(int4 c) {
    // c = [b,x,y,z]
    return ((((u32)c.x * 512u + ((u32)c.w >> 1)) * 512u + ((u32)c.z >> 1)) * 512u)
           + ((u32)c.y >> 1);
}

__global__ void fill_u32(u32* p, u32 v, u32 n) {
    u32 i = blockIdx.x * blockDim.x + threadIdx.x;
    if (i < n) p[i] = v;
}

// read coords once: linear records + bucket histogram
__global__ void phase_a(const int4* __restrict__ coords, u32* __restrict__ linrec,
                        u32* __restrict__ bcnt, int n) {
    int i = blockIdx.x * blockDim.x + threadIdx.x;
    if (i >= n) return;
    int4 c = coords[i];
    u32 key = make_key(c);
    u32 off = ((u32)c.y & 1u) | (((u32)c.z & 1u) << 1) | (((u32)c.w & 1u) << 2);
    linrec[i] = (key << 3) | off;            // 29-bit key + 3-bit child offset = 32 bits
    atomicAdd(&bcnt[key >> LBITS], 1u);
}

// exclusive scan of in[0..G), G multiple of 1024, G/1024 <= 32; out may alias in.
__global__ void scan_block(const u32* __restrict__ in, u32* __restrict__ out,
                           u32* __restrict__ out2, u32 G, u32* __restrict__ counter) {
    __shared__ u32 s[1024];
    int t = threadIdx.x;
    u32 items = G >> 10;
    u32 v[32]; u32 sum = 0;
    for (u32 j = 0; j < items; ++j) { v[j] = in[(u32)t * items + j]; sum += v[j]; }
    s[t] = sum; __syncthreads();
    for (int d = 1; d < 1024; d <<= 1) {
        u32 add = (t >= d) ? s[t - d] : 0u;
        __syncthreads(); s[t] += add; __syncthreads();
    }
    u32 excl = s[t] - sum;
    for (u32 j = 0; j < items; ++j) {
        u32 idx = (u32)t * items + j;
        u32 x = v[j];
        out[idx] = excl;
        if (out2) out2[idx] = excl;
        excl += x;
    }
    if (t == 1023) counter[0] = s[1023];
}

__global__ void scatter(const u32* __restrict__ linrec, u32* __restrict__ cursor,
                        u32* __restrict__ buckrec, int n) {
    int i = blockIdx.x * blockDim.x + threadIdx.x;
    if (i >= n) return;
    u32 rec = linrec[i];
    u32 pos = atomicAdd(&cursor[rec >> (LBITS + 3)], 1u);
    buckrec[pos] = rec;
}

// one wave per bucket: LDS bitmap -> unique count
__global__ void __launch_bounds__(256) pass_count(const u32* __restrict__ buckrec,
                                                  const u32* __restrict__ bbase,
                                                  u32* __restrict__ ucount, int n) {
    __shared__ u32 bm[BPB][BWORDS];
    u32 wave = threadIdx.x >> 6, lane = threadIdx.x & 63u;
    u32 bucket = blockIdx.x * BPB + wave;
    u32* B = bm[wave];
    #pragma unroll
    for (int j = 0; j < WPL; ++j) B[lane + 64u * j] = 0u;
    __syncthreads();
    u32 start = bbase[bucket];
    u32 end = (bucket + 1 < NBUCK) ? bbase[bucket + 1] : (u32)n;
    for (u32 i = start + lane; i < end; i += 64u) {
        u32 lk = (buckrec[i] >> 3) & LMASK;
        atomicOr(&B[lk >> 5], 1u << (lk & 31u));
    }
    __syncthreads();
    u32 sum = 0;
    #pragma unroll
    for (int j = 0; j < WPL; ++j) sum += __popc(B[lane * WPL + j]);
    u32 incl = sum;
    #pragma unroll
    for (int d = 1; d < 64; d <<= 1) {
        u32 t = __shfl_up(incl, d);
        if ((int)lane >= d) incl += t;
    }
    if (lane == 63u) ucount[bucket] = incl;
}

// one wave per bucket: rank + feats in LDS, coalesced emit
__global__ void __launch_bounds__(256) pass_emit(const u32* __restrict__ buckrec,
        const u32* __restrict__ bbase, const u32* __restrict__ ubase,
        const u32* __restrict__ ucount, const float* __restrict__ kern,
        float4* __restrict__ rows, float* __restrict__ feats, int n) {
    __shared__ u32 bm[BPB][BWORDS];
    __shared__ u16 wo[BPB][BWORDS];
    __shared__ float fl[BPB][FCAP];
    u32 wave = threadIdx.x >> 6, lane = threadIdx.x & 63u;
    u32 bucket = blockIdx.x * BPB + wave;
    u32* B = bm[wave];
    u16* WOF = wo[wave];
    float* F = fl[wave];
    #pragma unroll
    for (int j = 0; j < WPL; ++j) B[lane + 64u * j] = 0u;
    for (u32 j = lane; j < FCAP; j += 64u) F[j] = 0.f;
    __syncthreads();
    u32 start = bbase[bucket];
    u32 end = (bucket + 1 < NBUCK) ? bbase[bucket + 1] : (u32)n;
    for (u32 i = start + lane; i < end; i += 64u) {
        u32 lk = (buckrec[i] >> 3) & LMASK;
        atomicOr(&B[lk >> 5], 1u << (lk & 31u));
    }
    __syncthreads();
    u32 pc[WPL]; u32 sum = 0;
    #pragma unroll
    for (int j = 0; j < WPL; ++j) { pc[j] = __popc(B[lane * WPL + j]); sum += pc[j]; }
    u32 incl = sum;
    #pragma unroll
    for (int d = 1; d < 64; d <<= 1) {
        u32 t = __shfl_up(incl, d);
        if ((int)lane >= d) incl += t;
    }
    u32 lex = incl - sum;                 // lane-exclusive unique offset in bucket
    u32 e = lex;
    #pragma unroll
    for (int j = 0; j < WPL; ++j) { WOF[lane * WPL + j] = (u16)e; e += pc[j]; }
    __syncthreads();
    u32 base = ubase[bucket];
    u32 uc = ucount[bucket];
    bool lds_ok = (uc <= FCAP);
    for (u32 i = start + lane; i < end; i += 64u) {
        u32 rec = buckrec[i];
        u32 off = rec & 7u;
        float contrib = (float)(1u << off) * kern[off];
        u32 lk = (rec >> 3) & LMASK;
        u32 w = lk >> 5, bit = lk & 31u;
        u32 r = (u32)WOF[w] + (u32)__popc(B[w] & ((1u << bit) - 1u));
        if (lds_ok) atomicAdd(&F[r], contrib);
        else        atomicAdd(&feats[base + r], contrib);   // feats pre-zeroed
    }
    __syncthreads();
    // emit coord rows in ascending key order -> rank-sequential (coalesced)
    u32 rank = base + lex;
    u32 keyhi = bucket << LBITS;
    #pragma unroll
    for (int j = 0; j < WPL; ++j) {
        u32 bits = B[lane * WPL + j];
        u32 kb = keyhi | ((lane * (u32)WPL + (u32)j) << 5);
        while (bits) {
            u32 t = __builtin_ctz(bits);
            bits &= bits - 1u;
            u32 key = kb | t;
            rows[rank++] = make_float4((float)(key >> 27), (float)(key & 511u),
                                       (float)((key >> 9) & 511u),
                                       (float)((key >> 18) & 511u));
        }
    }
    if (lds_ok) {
        for (u32 j = lane; j < uc; j += 64u) feats[base + j] = F[j];
    }
}

__global__ void pad_fill(float4* __restrict__ rows, const u32* __restrict__ counter, int n) {
    int i = blockIdx.x * blockDim.x + threadIdx.x;
    if (i < n && (u32)i >= counter[0]) rows[i] = make_float4(-1.f, -1.f, -1.f, -1.f);
}

extern "C" void kernel_launch(void* const* d_in, const int* in_sizes, int n_in,
                              void* d_out, int out_size, void* d_ws, size_t ws_size,
                              hipStream_t stream) {
    const int n = in_sizes[0] / 4;               // 4,000,000 points
    const int4* coords = (const int4*)d_in[0];
    const float* kern  = (const float*)d_in[1];

    u32* wsp = (u32*)d_ws;
    u32* linrec  = wsp;                  // n
    u32* buckrec = linrec + n;           // n
    u32* bcnt    = buckrec + n;          // NBUCK  (becomes bbase in place)
    u32* counter = bcnt + NBUCK;         // 2 (adjacent to bcnt for joint zero-fill)
    u32* cursor  = counter + 2;          // NBUCK
    u32* ucount  = cursor + NBUCK;       // NBUCK
    u32* ubase   = ucount + NBUCK;       // NBUCK   — total ~32.5 MB

    float4* rows  = (float4*)d_out;                              // n rows
    float*  feats = (float*)((char*)d_out + (size_t)n * 16);     // n fp32

    fill_u32<<<((u32)n + 255) / 256, 256, 0, stream>>>((u32*)feats, 0u, (u32)n);
    fill_u32<<<(NBUCK + 2 + 255) / 256, 256, 0, stream>>>(bcnt, 0u, NBUCK + 2);

    phase_a<<<((u32)n + 255) / 256, 256, 0, stream>>>(coords, linrec, bcnt, n);
    scan_block<<<1, 1024, 0, stream>>>(bcnt, bcnt, cursor, NBUCK, counter + 1);
    scatter<<<((u32)n + 255) / 256, 256, 0, stream>>>(linrec, cursor, buckrec, n);
    pass_count<<<NBUCK / BPB, 256, 0, stream>>>(buckrec, bcnt, ucount, n);
    scan_block<<<1, 1024, 0, stream>>>(ucount, ubase, (u32*)nullptr, NBUCK, counter);
    pass_emit<<<NBUCK / BPB, 256, 0, stream>>>(buckrec, bcnt, ubase, ucount, kern,
                                               rows, feats, n);
    pad_fill<<<((u32)n + 255) / 256, 256, 0, stream>>>(rows, counter, n);
}

// Round 6
// 507.035 us; speedup vs baseline: 1.4606x; 1.4606x over previous
//
#include <hip/hip_runtime.h>
#include <stdint.h>

typedef unsigned int u32;
typedef unsigned long long u64;
typedef unsigned short u16;

// key = ((b*512 + z/2)*512 + y/2)*512 + x/2  in [0, 2^29)
// rec = (key<<3)|off. coarse = rec>>24 (8b), fine = (rec>>17)&127 (7b),
// bucket = key>>14 = rec>>17 (15b), local key = key & 0x3FFF (14b).
#define LBITS  14
#define LMASK  ((1u << LBITS) - 1u)
#define NBUCK  (1u << (29 - LBITS))      // 32768 fine buckets
#define BWORDS (1u << (LBITS - 5))       // 512 u32 bitmap words / bucket
#define WPL    (BWORDS / 64)             // 8 words per lane
#define FCAP   320                       // LDS feats slots per bucket
#define BPB    4                         // buckets (waves) per 256-thr block
#define TILE_A 8192                      // phase_a / part1 tile (32 rec/thread)

__device__ __forceinline__ u32 make_key(int4 c) {
    return ((((u32)c.x * 512u + ((u32)c.w >> 1)) * 512u + ((u32)c.z >> 1)) * 512u)
           + ((u32)c.y >> 1);
}

__global__ void fill_u32(u32* p, u32 v, u32 n) {
    u32 i = blockIdx.x * blockDim.x + threadIdx.x;
    if (i < n) p[i] = v;
}

// ---- phase A: coords -> linrec + per-tile coarse histogram (bin-major matrix)
__global__ void phase_a(const int4* __restrict__ coords, u32* __restrict__ linrec,
                        u32* __restrict__ histmat, int n, u32 NT) {
    __shared__ u32 h[256];
    int t = threadIdx.x;
    h[t] = 0; __syncthreads();
    u32 base = blockIdx.x * TILE_A;
    u32 m = min((u32)TILE_A, (u32)n - base);
    for (u32 j = t; j < m; j += 256u) {
        int4 c = coords[base + j];
        u32 key = make_key(c);
        u32 off = ((u32)c.y & 1u) | (((u32)c.z & 1u) << 1) | (((u32)c.w & 1u) << 2);
        u32 rec = (key << 3) | off;
        linrec[base + j] = rec;
        atomicAdd(&h[rec >> 24], 1u);
    }
    __syncthreads();
    histmat[(u32)t * NT + blockIdx.x] = h[t];   // bin-major: scan order = radix order
}

// ---- generic single-block chunked exclusive scan (any G); out may alias data
__global__ void exscan(const u32* __restrict__ data, u32* __restrict__ out, u32 G,
                       u32* __restrict__ total) {
    __shared__ u32 s[1024];
    int t = threadIdx.x;
    u32 I = (G + 1023u) >> 10;
    u32 lo = (u32)t * I, hi = min(lo + I, G);
    u32 sum = 0;
    for (u32 j = lo; j < hi; ++j) sum += data[j];
    s[t] = sum; __syncthreads();
    for (int d = 1; d < 1024; d <<= 1) {
        u32 add = (t >= d) ? s[t - d] : 0u;
        __syncthreads(); s[t] += add; __syncthreads();
    }
    u32 run = s[t] - sum;
    for (u32 j = lo; j < hi; ++j) { u32 v = data[j]; out[j] = run; run += v; }
    if (total && t == 1023) total[0] = s[1023];
}

// ---- part1: coarse scatter, bases from scanned histmat, LDS cursors only
__global__ void part1(const u32* __restrict__ linrec, const u32* __restrict__ histmat,
                      u32* __restrict__ tmp, int n, u32 NT) {
    __shared__ u32 cur[256];
    int t = threadIdx.x;
    cur[t] = histmat[(u32)t * NT + blockIdx.x];
    __syncthreads();
    u32 base = blockIdx.x * TILE_A;
    u32 m = min((u32)TILE_A, (u32)n - base);
    for (u32 j = t; j < m; j += 256u) {
        u32 rec = linrec[base + j];               // L2-warm
        u32 pos = atomicAdd(&cur[rec >> 24], 1u); // LDS atomic
        tmp[pos] = rec;                           // scattered 4B, L2-merged per tile window
    }
}

// ---- part2: one block per coarse bucket -> fine order + bbase
__global__ void part2(const u32* __restrict__ tmp, const u32* __restrict__ histmat,
                      u32* __restrict__ buckrec, u32* __restrict__ bbase, int n, u32 NT) {
    __shared__ u32 h[128], sc[128], cur[128];
    int t = threadIdx.x;
    u32 c = blockIdx.x;
    u32 start = histmat[c * NT];
    u32 end = (c == 255u) ? (u32)n : histmat[(c + 1u) * NT];
    if (t < 128) h[t] = 0;
    __syncthreads();
    for (u32 i = start + t; i < end; i += 256u)
        atomicAdd(&h[(tmp[i] >> 17) & 127u], 1u);
    __syncthreads();
    if (t < 128) sc[t] = h[t];
    __syncthreads();
    for (int d = 1; d < 128; d <<= 1) {
        u32 add = (t < 128 && t >= d) ? sc[t - d] : 0u;
        __syncthreads();
        if (t < 128) sc[t] += add;
        __syncthreads();
    }
    if (t < 128) {
        u32 ex = start + sc[t] - h[t];
        bbase[(c << 7) | (u32)t] = ex;
        cur[t] = ex;
    }
    __syncthreads();
    for (u32 i = start + t; i < end; i += 256u) {
        u32 rec = tmp[i];                                  // L2-warm (just written)
        u32 pos = atomicAdd(&cur[(rec >> 17) & 127u], 1u); // LDS atomic
        buckrec[pos] = rec;                                // 64 KB block window, L2-merged
    }
}

// ---- one wave per fine bucket: LDS bitmap -> unique count
__global__ void __launch_bounds__(256) pass_count(const u32* __restrict__ buckrec,
                                                  const u32* __restrict__ bbase,
                                                  u32* __restrict__ ucount, int n) {
    __shared__ u32 bm[BPB][BWORDS];
    u32 wave = threadIdx.x >> 6, lane = threadIdx.x & 63u;
    u32 bucket = blockIdx.x * BPB + wave;
    u32* B = bm[wave];
    #pragma unroll
    for (int j = 0; j < WPL; ++j) B[lane + 64u * j] = 0u;
    __syncthreads();
    u32 start = bbase[bucket];
    u32 end = (bucket + 1 < NBUCK) ? bbase[bucket + 1] : (u32)n;
    for (u32 i = start + lane; i < end; i += 64u) {
        u32 lk = (buckrec[i] >> 3) & LMASK;
        atomicOr(&B[lk >> 5], 1u << (lk & 31u));
    }
    __syncthreads();
    u32 sum = 0;
    #pragma unroll
    for (int j = 0; j < WPL; ++j) sum += __popc(B[lane * WPL + j]);
    u32 incl = sum;
    #pragma unroll
    for (int d = 1; d < 64; d <<= 1) {
        u32 t = __shfl_up(incl, d);
        if ((int)lane >= d) incl += t;
    }
    if (lane == 63u) ucount[bucket] = incl;
}

// ---- one wave per fine bucket: rank + feats in LDS, coalesced emit
__global__ void __launch_bounds__(256) pass_emit(const u32* __restrict__ buckrec,
        const u32* __restrict__ bbase, const u32* __restrict__ ubase,
        const u32* __restrict__ ucount, const float* __restrict__ kern,
        float4* __restrict__ rows, float* __restrict__ feats, int n) {
    __shared__ u32 bm[BPB][BWORDS];
    __shared__ u16 wo[BPB][BWORDS];
    __shared__ float fl[BPB][FCAP];
    u32 wave = threadIdx.x >> 6, lane = threadIdx.x & 63u;
    u32 bucket = blockIdx.x * BPB + wave;
    u32* B = bm[wave];
    u16* WOF = wo[wave];
    float* F = fl[wave];
    #pragma unroll
    for (int j = 0; j < WPL; ++j) B[lane + 64u * j] = 0u;
    for (u32 j = lane; j < FCAP; j += 64u) F[j] = 0.f;
    __syncthreads();
    u32 start = bbase[bucket];
    u32 end = (bucket + 1 < NBUCK) ? bbase[bucket + 1] : (u32)n;
    for (u32 i = start + lane; i < end; i += 64u) {
        u32 lk = (buckrec[i] >> 3) & LMASK;
        atomicOr(&B[lk >> 5], 1u << (lk & 31u));
    }
    __syncthreads();
    u32 pc[WPL]; u32 sum = 0;
    #pragma unroll
    for (int j = 0; j < WPL; ++j) { pc[j] = __popc(B[lane * WPL + j]); sum += pc[j]; }
    u32 incl = sum;
    #pragma unroll
    for (int d = 1; d < 64; d <<= 1) {
        u32 t = __shfl_up(incl, d);
        if ((int)lane >= d) incl += t;
    }
    u32 lex = incl - sum;
    u32 e = lex;
    #pragma unroll
    for (int j = 0; j < WPL; ++j) { WOF[lane * WPL + j] = (u16)e; e += pc[j]; }
    __syncthreads();
    u32 base = ubase[bucket];
    u32 uc = ucount[bucket];
    bool lds_ok = (uc <= FCAP);
    for (u32 i = start + lane; i < end; i += 64u) {
        u32 rec = buckrec[i];
        u32 off = rec & 7u;
        float contrib = (float)(1u << off) * kern[off];
        u32 lk = (rec >> 3) & LMASK;
        u32 w = lk >> 5, bit = lk & 31u;
        u32 r = (u32)WOF[w] + (u32)__popc(B[w] & ((1u << bit) - 1u));
        if (lds_ok) atomicAdd(&F[r], contrib);
        else        atomicAdd(&feats[base + r], contrib);   // feats pre-zeroed
    }
    __syncthreads();
    u32 rank = base + lex;
    u32 keyhi = bucket << LBITS;
    #pragma unroll
    for (int j = 0; j < WPL; ++j) {
        u32 bits = B[lane * WPL + j];
        u32 kb = keyhi | ((lane * (u32)WPL + (u32)j) << 5);
        while (bits) {
            u32 t = __builtin_ctz(bits);
            bits &= bits - 1u;
            u32 key = kb | t;
            rows[rank++] = make_float4((float)(key >> 27), (float)(key & 511u),
                                       (float)((key >> 9) & 511u),
                                       (float)((key >> 18) & 511u));
        }
    }
    if (lds_ok) {
        for (u32 j = lane; j < uc; j += 64u) feats[base + j] = F[j];
    }
}

__global__ void pad_fill(float4* __restrict__ rows, const u32* __restrict__ counter, int n) {
    int i = blockIdx.x * blockDim.x + threadIdx.x;
    if (i < n && (u32)i >= counter[0]) rows[i] = make_float4(-1.f, -1.f, -1.f, -1.f);
}

extern "C" void kernel_launch(void* const* d_in, const int* in_sizes, int n_in,
                              void* d_out, int out_size, void* d_ws, size_t ws_size,
                              hipStream_t stream) {
    const int n = in_sizes[0] / 4;               // 4,000,000 points
    const int4* coords = (const int4*)d_in[0];
    const float* kern  = (const float*)d_in[1];
    const u32 NT = ((u32)n + TILE_A - 1) / TILE_A;   // tiles (=489)

    u32* wsp = (u32*)d_ws;
    u32* linrec  = wsp;                    // n   (reused as buckrec by part2)
    u32* tmp     = linrec + n;             // n
    u32* histmat = tmp + n;                // 256*NT
    u32* bbase   = histmat + 256 * NT;     // NBUCK
    u32* ucount  = bbase + NBUCK;          // NBUCK
    u32* ubase   = ucount + NBUCK;         // NBUCK
    u32* counter = ubase + NBUCK;          // 1
    u32* buckrec = linrec;                 // part2 output overwrites linrec

    float4* rows  = (float4*)d_out;                              // n rows
    float*  feats = (float*)((char*)d_out + (size_t)n * 16);     // n fp32

    fill_u32<<<((u32)n + 255) / 256, 256, 0, stream>>>((u32*)feats, 0u, (u32)n);

    phase_a<<<NT, 256, 0, stream>>>(coords, linrec, histmat, n, NT);
    exscan<<<1, 1024, 0, stream>>>(histmat, histmat, 256 * NT, (u32*)nullptr);
    part1<<<NT, 256, 0, stream>>>(linrec, histmat, tmp, n, NT);
    part2<<<256, 256, 0, stream>>>(tmp, histmat, buckrec, bbase, n, NT);
    pass_count<<<NBUCK / BPB, 256, 0, stream>>>(buckrec, bbase, ucount, n);
    exscan<<<1, 1024, 0, stream>>>(ucount, ubase, NBUCK, counter);
    pass_emit<<<NBUCK / BPB, 256, 0, stream>>>(buckrec, bbase, ubase, ucount, kern,
                                               rows, feats, n);
    pad_fill<<<((u32)n + 255) / 256, 256, 0, stream>>>(rows, counter, n);
}

// Round 7
// 279.985 us; speedup vs baseline: 2.6450x; 1.8109x over previous
//
#include <hip/hip_runtime.h>
#include <stdint.h>

typedef unsigned int u32;
typedef unsigned long long u64;
typedef unsigned short u16;

// key = ((b*512 + z/2)*512 + y/2)*512 + x/2  in [0, 2^29)
// rec = (key<<3)|off. coarse = rec>>24 (8b), fine = (rec>>17)&127 (7b),
// bucket = key>>14 = rec>>17 (15b), local key = key & 0x3FFF (14b).
#define LBITS  14
#define LMASK  ((1u << LBITS) - 1u)
#define NBUCK  (1u << (29 - LBITS))      // 32768 fine buckets
#define BWORDS (1u << (LBITS - 5))       // 512 u32 bitmap words / bucket
#define WPL    (BWORDS / 64)             // 8 words per lane
#define FCAP   320                       // LDS feats slots per bucket
#define BPB    4                         // buckets (waves) per 256-thr block
#define TILE_A 8192                      // phase_a / part1 tile
#define SCAN_ELEM 2048                   // hierarchical scan: elems per block

__device__ __forceinline__ u32 make_key(int4 c) {
    return ((((u32)c.x * 512u + ((u32)c.w >> 1)) * 512u + ((u32)c.z >> 1)) * 512u)
           + ((u32)c.y >> 1);
}

__global__ void fill_u32(u32* p, u32 v, u32 n) {
    u32 i = blockIdx.x * blockDim.x + threadIdx.x;
    if (i < n) p[i] = v;
}

// ---- phase A: coords -> linrec + per-tile coarse histogram (bin-major matrix)
__global__ void phase_a(const int4* __restrict__ coords, u32* __restrict__ linrec,
                        u32* __restrict__ histmat, int n, u32 NT) {
    __shared__ u32 h[256];
    int t = threadIdx.x;
    h[t] = 0; __syncthreads();
    u32 base = blockIdx.x * TILE_A;
    u32 m = min((u32)TILE_A, (u32)n - base);
    for (u32 j = t; j < m; j += 256u) {
        int4 c = coords[base + j];
        u32 key = make_key(c);
        u32 off = ((u32)c.y & 1u) | (((u32)c.z & 1u) << 1) | (((u32)c.w & 1u) << 2);
        u32 rec = (key << 3) | off;
        linrec[base + j] = rec;
        atomicAdd(&h[rec >> 24], 1u);
    }
    __syncthreads();
    histmat[(u32)t * NT + blockIdx.x] = h[t];   // bin-major: scan order = radix order
}

// ---- hierarchical exclusive scan: reduce -> small scan -> apply ----
__global__ void scan_reduce(const u32* __restrict__ data, u32* __restrict__ partial, u32 G) {
    __shared__ u32 s[256];
    u32 t = threadIdx.x;
    u32 base = blockIdx.x * SCAN_ELEM + t * 8u;
    u32 sum = 0;
    #pragma unroll
    for (int j = 0; j < 8; ++j) { u32 idx = base + j; if (idx < G) sum += data[idx]; }
    s[t] = sum; __syncthreads();
    for (int d = 128; d > 0; d >>= 1) { if ((int)t < d) s[t] += s[t + d]; __syncthreads(); }
    if (t == 0) partial[blockIdx.x] = s[0];
}

// single block, NB <= 256: exclusive scan of partial in place; total -> counter
__global__ void scan_small(u32* __restrict__ partial, u32 NB, u32* __restrict__ total) {
    __shared__ u32 s[256];
    u32 t = threadIdx.x;
    u32 v = (t < NB) ? partial[t] : 0u;
    s[t] = v; __syncthreads();
    for (int d = 1; d < 256; d <<= 1) {
        u32 add = (t >= (u32)d) ? s[t - d] : 0u;
        __syncthreads(); s[t] += add; __syncthreads();
    }
    if (t < NB) partial[t] = s[t] - v;
    if (total && t == 255u) total[0] = s[255];
}

__global__ void scan_apply(const u32* __restrict__ data, u32* __restrict__ out,
                           const u32* __restrict__ partial, u32 G) {
    __shared__ u32 s[256];
    u32 t = threadIdx.x;
    u32 base = blockIdx.x * SCAN_ELEM + t * 8u;
    u32 v[8]; u32 sum = 0;
    #pragma unroll
    for (int j = 0; j < 8; ++j) {
        u32 idx = base + j;
        v[j] = (idx < G) ? data[idx] : 0u;
        sum += v[j];
    }
    s[t] = sum; __syncthreads();
    for (int d = 1; d < 256; d <<= 1) {
        u32 add = (t >= (u32)d) ? s[t - d] : 0u;
        __syncthreads(); s[t] += add; __syncthreads();
    }
    u32 run = s[t] - sum + partial[blockIdx.x];
    #pragma unroll
    for (int j = 0; j < 8; ++j) {
        u32 idx = base + j;
        if (idx < G) { u32 x = v[j]; out[idx] = run; run += x; }
    }
}

// ---- part1: coarse scatter, bases from scanned histmat, LDS cursors only
__global__ void part1(const u32* __restrict__ linrec, const u32* __restrict__ histmat,
                      u32* __restrict__ tmp, int n, u32 NT) {
    __shared__ u32 cur[256];
    int t = threadIdx.x;
    cur[t] = histmat[(u32)t * NT + blockIdx.x];
    __syncthreads();
    u32 base = blockIdx.x * TILE_A;
    u32 m = min((u32)TILE_A, (u32)n - base);
    for (u32 j = t; j < m; j += 256u) {
        u32 rec = linrec[base + j];
        u32 pos = atomicAdd(&cur[rec >> 24], 1u);  // LDS atomic
        tmp[pos] = rec;
    }
}

// ---- part2: one block per coarse bucket -> fine order + bbase
__global__ void part2(const u32* __restrict__ tmp, const u32* __restrict__ histmat,
                      u32* __restrict__ buckrec, u32* __restrict__ bbase, int n, u32 NT) {
    __shared__ u32 h[128], sc[128], cur[128];
    int t = threadIdx.x;
    u32 c = blockIdx.x;
    u32 start = histmat[c * NT];
    u32 end = (c == 255u) ? (u32)n : histmat[(c + 1u) * NT];
    if (t < 128) h[t] = 0;
    __syncthreads();
    for (u32 i = start + t; i < end; i += 256u)
        atomicAdd(&h[(tmp[i] >> 17) & 127u], 1u);
    __syncthreads();
    if (t < 128) sc[t] = h[t];
    __syncthreads();
    for (int d = 1; d < 128; d <<= 1) {
        u32 add = (t < 128 && t >= d) ? sc[t - d] : 0u;
        __syncthreads();
        if (t < 128) sc[t] += add;
        __syncthreads();
    }
    if (t < 128) {
        u32 ex = start + sc[t] - h[t];
        bbase[(c << 7) | (u32)t] = ex;
        cur[t] = ex;
    }
    __syncthreads();
    for (u32 i = start + t; i < end; i += 256u) {
        u32 rec = tmp[i];
        u32 pos = atomicAdd(&cur[(rec >> 17) & 127u], 1u); // LDS atomic
        buckrec[pos] = rec;
    }
}

// ---- one wave per fine bucket: LDS bitmap -> unique count
__global__ void __launch_bounds__(256) pass_count(const u32* __restrict__ buckrec,
                                                  const u32* __restrict__ bbase,
                                                  u32* __restrict__ ucount, int n) {
    __shared__ u32 bm[BPB][BWORDS];
    u32 wave = threadIdx.x >> 6, lane = threadIdx.x & 63u;
    u32 bucket = blockIdx.x * BPB + wave;
    u32* B = bm[wave];
    #pragma unroll
    for (int j = 0; j < WPL; ++j) B[lane + 64u * j] = 0u;
    __syncthreads();
    u32 start = bbase[bucket];
    u32 end = (bucket + 1 < NBUCK) ? bbase[bucket + 1] : (u32)n;
    for (u32 i = start + lane; i < end; i += 64u) {
        u32 lk = (buckrec[i] >> 3) & LMASK;
        atomicOr(&B[lk >> 5], 1u << (lk & 31u));
    }
    __syncthreads();
    u32 sum = 0;
    #pragma unroll
    for (int j = 0; j < WPL; ++j) sum += __popc(B[lane * WPL + j]);
    u32 incl = sum;
    #pragma unroll
    for (int d = 1; d < 64; d <<= 1) {
        u32 t = __shfl_up(incl, d);
        if ((int)lane >= d) incl += t;
    }
    if (lane == 63u) ucount[bucket] = incl;
}

// ---- one wave per fine bucket: rank + feats in LDS, coalesced emit
__global__ void __launch_bounds__(256) pass_emit(const u32* __restrict__ buckrec,
        const u32* __restrict__ bbase, const u32* __restrict__ ubase,
        const u32* __restrict__ ucount, const float* __restrict__ kern,
        float4* __restrict__ rows, float* __restrict__ feats, int n) {
    __shared__ u32 bm[BPB][BWORDS];
    __shared__ u16 wo[BPB][BWORDS];
    __shared__ float fl[BPB][FCAP];
    u32 wave = threadIdx.x >> 6, lane = threadIdx.x & 63u;
    u32 bucket = blockIdx.x * BPB + wave;
    u32* B = bm[wave];
    u16* WOF = wo[wave];
    float* F = fl[wave];
    #pragma unroll
    for (int j = 0; j < WPL; ++j) B[lane + 64u * j] = 0u;
    for (u32 j = lane; j < FCAP; j += 64u) F[j] = 0.f;
    __syncthreads();
    u32 start = bbase[bucket];
    u32 end = (bucket + 1 < NBUCK) ? bbase[bucket + 1] : (u32)n;
    for (u32 i = start + lane; i < end; i += 64u) {
        u32 lk = (buckrec[i] >> 3) & LMASK;
        atomicOr(&B[lk >> 5], 1u << (lk & 31u));
    }
    __syncthreads();
    u32 pc[WPL]; u32 sum = 0;
    #pragma unroll
    for (int j = 0; j < WPL; ++j) { pc[j] = __popc(B[lane * WPL + j]); sum += pc[j]; }
    u32 incl = sum;
    #pragma unroll
    for (int d = 1; d < 64; d <<= 1) {
        u32 t = __shfl_up(incl, d);
        if ((int)lane >= d) incl += t;
    }
    u32 lex = incl - sum;
    u32 e = lex;
    #pragma unroll
    for (int j = 0; j < WPL; ++j) { WOF[lane * WPL + j] = (u16)e; e += pc[j]; }
    __syncthreads();
    u32 base = ubase[bucket];
    u32 uc = ucount[bucket];
    bool lds_ok = (uc <= FCAP);
    for (u32 i = start + lane; i < end; i += 64u) {
        u32 rec = buckrec[i];
        u32 off = rec & 7u;
        float contrib = (float)(1u << off) * kern[off];
        u32 lk = (rec >> 3) & LMASK;
        u32 w = lk >> 5, bit = lk & 31u;
        u32 r = (u32)WOF[w] + (u32)__popc(B[w] & ((1u << bit) - 1u));
        if (lds_ok) atomicAdd(&F[r], contrib);
        else        atomicAdd(&feats[base + r], contrib);   // feats pre-zeroed
    }
    __syncthreads();
    u32 rank = base + lex;
    u32 keyhi = bucket << LBITS;
    #pragma unroll
    for (int j = 0; j < WPL; ++j) {
        u32 bits = B[lane * WPL + j];
        u32 kb = keyhi | ((lane * (u32)WPL + (u32)j) << 5);
        while (bits) {
            u32 t = __builtin_ctz(bits);
            bits &= bits - 1u;
            u32 key = kb | t;
            rows[rank++] = make_float4((float)(key >> 27), (float)(key & 511u),
                                       (float)((key >> 9) & 511u),
                                       (float)((key >> 18) & 511u));
        }
    }
    if (lds_ok) {
        for (u32 j = lane; j < uc; j += 64u) feats[base + j] = F[j];
    }
}

__global__ void pad_fill(float4* __restrict__ rows, const u32* __restrict__ counter, int n) {
    int i = blockIdx.x * blockDim.x + threadIdx.x;
    if (i < n && (u32)i >= counter[0]) rows[i] = make_float4(-1.f, -1.f, -1.f, -1.f);
}

extern "C" void kernel_launch(void* const* d_in, const int* in_sizes, int n_in,
                              void* d_out, int out_size, void* d_ws, size_t ws_size,
                              hipStream_t stream) {
    const int n = in_sizes[0] / 4;               // 4,000,000 points
    const int4* coords = (const int4*)d_in[0];
    const float* kern  = (const float*)d_in[1];
    const u32 NT = ((u32)n + TILE_A - 1) / TILE_A;   // tiles (=489)
    const u32 G1 = 256 * NT;                          // histmat entries (=125184)
    const u32 NB1 = (G1 + SCAN_ELEM - 1) / SCAN_ELEM; // 62
    const u32 NB2 = (NBUCK + SCAN_ELEM - 1) / SCAN_ELEM; // 16

    u32* wsp = (u32*)d_ws;
    u32* linrec  = wsp;                    // n   (reused as buckrec by part2)
    u32* tmp     = linrec + n;             // n
    u32* histmat = tmp + n;                // 256*NT
    u32* bbase   = histmat + G1;           // NBUCK
    u32* ucount  = bbase + NBUCK;          // NBUCK
    u32* ubase   = ucount + NBUCK;         // NBUCK
    u32* counter = ubase + NBUCK;          // 1
    u32* spart   = counter + 4;            // 256 scan partials
    u32* buckrec = linrec;                 // part2 output overwrites linrec

    float4* rows  = (float4*)d_out;                              // n rows
    float*  feats = (float*)((char*)d_out + (size_t)n * 16);     // n fp32

    fill_u32<<<((u32)n + 255) / 256, 256, 0, stream>>>((u32*)feats, 0u, (u32)n);

    phase_a<<<NT, 256, 0, stream>>>(coords, linrec, histmat, n, NT);
    scan_reduce<<<NB1, 256, 0, stream>>>(histmat, spart, G1);
    scan_small<<<1, 256, 0, stream>>>(spart, NB1, (u32*)nullptr);
    scan_apply<<<NB1, 256, 0, stream>>>(histmat, histmat, spart, G1);
    part1<<<NT, 256, 0, stream>>>(linrec, histmat, tmp, n, NT);
    part2<<<256, 256, 0, stream>>>(tmp, histmat, buckrec, bbase, n, NT);
    pass_count<<<NBUCK / BPB, 256, 0, stream>>>(buckrec, bbase, ucount, n);
    scan_reduce<<<NB2, 256, 0, stream>>>(ucount, spart, NBUCK);
    scan_small<<<1, 256, 0, stream>>>(spart, NB2, counter);
    scan_apply<<<NB2, 256, 0, stream>>>(ucount, ubase, spart, NBUCK);
    pass_emit<<<NBUCK / BPB, 256, 0, stream>>>(buckrec, bbase, ubase, ucount, kern,
                                               rows, feats, n);
    pad_fill<<<((u32)n + 255) / 256, 256, 0, stream>>>(rows, counter, n);
}